// Round 2
// baseline (449.557 us; speedup 1.0000x reference)
//
#include <hip/hip_runtime.h>
#include <hip/hip_bf16.h>
#include <math.h>

typedef __attribute__((ext_vector_type(8))) short  short8;   // 8 bf16 (4 VGPRs) - MFMA A/B frag
typedef __attribute__((ext_vector_type(4))) float  floatx4;  // MFMA C/D frag
typedef __attribute__((ext_vector_type(4))) unsigned int uintx4; // 16B vector load

#define NLOCI 8
#define VOCAB 512
#define DDIM  256
#define HID   512
#define NSAMP (8192 * 16)

__device__ __forceinline__ float bf_lo(unsigned int w) {
    union { unsigned int u; float f; } c; c.u = w << 16; return c.f;
}
__device__ __forceinline__ float bf_hi(unsigned int w) {
    union { unsigned int u; float f; } c; c.u = w & 0xFFFF0000u; return c.f;
}
__device__ __forceinline__ unsigned short f2bf(float f) {
    union { float f; unsigned int u; } c; c.f = f;
    unsigned int u = c.u;
    return (unsigned short)((u + 0x7FFFu + ((u >> 16) & 1u)) >> 16);  // RNE
}
__device__ __forceinline__ float geluf(float x) {
    return 0.5f * x * (1.0f + erff(x * 0.70710678118654752f));  // exact erf GELU
}

// ---------------------------------------------------------------------------
// Kernel 1: T'[l] = tables[l] (512x256) @ W1[l*256:(l+1)*256] (256x512)
// f32 inputs -> bf16 output. grid = 8 loci * 8 vblocks * 8 nblocks = 512 blocks.
// ---------------------------------------------------------------------------
__global__ __launch_bounds__(256) void k_fuse_tables(
    const float* __restrict__ tables,   // [8][512][256] f32
    const float* __restrict__ W1,       // [2048][512] f32
    unsigned short* __restrict__ Tp)    // [8][512][512] bf16
{
    const int l  = blockIdx.x >> 6;
    const int v0 = ((blockIdx.x >> 3) & 7) * 64;
    const int n0 = (blockIdx.x & 7) * 64;

    __shared__ unsigned short a_lds[64 * 264];   // tables tile (bf16), pad +8
    __shared__ unsigned short bt_lds[64 * 264];  // W1^T tile: bt[n][k] (bf16)

    const int t = threadIdx.x;

    // stage A: 64 rows x 256 cols, f32 -> bf16
    {
        const float* src = tables + (l * 512 + v0) * 256;
#pragma unroll
        for (int i = 0; i < 16; ++i) {
            int flat = i * 1024 + t * 4;
            int row = flat >> 8, col = flat & 255;
            float4 v = *(const float4*)(src + flat);
            ushort4 pk;
            pk.x = f2bf(v.x); pk.y = f2bf(v.y); pk.z = f2bf(v.z); pk.w = f2bf(v.w);
            *(ushort4*)(a_lds + row * 264 + col) = pk;
        }
    }
    // stage B^T: bt[n][k] = bf16(W1[l*256+k][n0+n])  (coalesced across n)
    {
        const int n = t & 63;
        const int kq = t >> 6;  // 0..3
#pragma unroll
        for (int i = 0; i < 64; ++i) {
            int k = i * 4 + kq;
            bt_lds[n * 264 + k] = f2bf(W1[(l * 256 + k) * 512 + n0 + n]);
        }
    }
    __syncthreads();

    const int wave = t >> 6, lane = t & 63;
    const int p = lane & 15, q = lane >> 4;

    floatx4 acc[4];
#pragma unroll
    for (int nt = 0; nt < 4; ++nt) acc[nt] = (floatx4){0.f, 0.f, 0.f, 0.f};

#pragma unroll
    for (int kc = 0; kc < 8; ++kc) {
        short8 afrag = *(const short8*)(a_lds + (wave * 16 + p) * 264 + kc * 32 + q * 8);
#pragma unroll
        for (int nt = 0; nt < 4; ++nt) {
            short8 bfrag = *(const short8*)(bt_lds + (nt * 16 + p) * 264 + kc * 32 + q * 8);
            acc[nt] = __builtin_amdgcn_mfma_f32_16x16x32_bf16(afrag, bfrag, acc[nt], 0, 0, 0);
        }
    }

    // D: row(M=vocab) = q*4 + r, col(N) = nt*16 + p
#pragma unroll
    for (int nt = 0; nt < 4; ++nt)
#pragma unroll
        for (int r = 0; r < 4; ++r) {
            int row = v0 + wave * 16 + q * 4 + r;
            int col = n0 + nt * 16 + p;
            Tp[(l * 512 + row) * 512 + col] = f2bf(acc[nt][r]);
        }
}

// ---------------------------------------------------------------------------
// Kernel 1b: W2t[n][k] = bf16(W2[k][n])
// ---------------------------------------------------------------------------
__global__ __launch_bounds__(256) void k_transpose_w2(
    const float* __restrict__ W2,        // [512][256] f32
    unsigned short* __restrict__ W2t)    // [256][512] bf16
{
    int tid = blockIdx.x * 256 + threadIdx.x;  // 131072
    int n = tid >> 9, k = tid & 511;
    W2t[tid] = f2bf(W2[k * 256 + n]);
}

// ---------------------------------------------------------------------------
// Kernel 2: fused gather + bias + GELU + (h @ W2 + b2)
// block = 256 threads (4 waves), 128 samples/block; grid = 131072/128 = 1024
// ---------------------------------------------------------------------------
__global__ __launch_bounds__(256, 2) void k_main(
    const int* __restrict__ hap,              // [131072][8] int32
    const unsigned short* __restrict__ Tp,    // [8][512][512] bf16
    const float* __restrict__ b1,             // [512] f32
    const unsigned short* __restrict__ W2t,   // [256][512] bf16
    const float* __restrict__ b2,             // [256] f32
    float* __restrict__ out)                  // [131072][256] f32
{
    __shared__ unsigned short w2_lds[256 * 136];  // [n][k_local 0..127], pad->136

    const int t = threadIdx.x;
    const int wave = t >> 6, lane = t & 63;
    const int p = lane & 15, q = lane >> 4;
    const int m_block = blockIdx.x * 128;

    // Per-lane byte offsets of the 8 T' rows for this lane's samples.
    int offs[2][8];
#pragma unroll
    for (int mt = 0; mt < 2; ++mt) {
        int m = m_block + wave * 32 + mt * 16 + p;
        const uintx4* hp = (const uintx4*)(hap + m * 8);
        uintx4 h0 = hp[0], h1 = hp[1];
        int tok[8] = {(int)h0[0], (int)h0[1], (int)h0[2], (int)h0[3],
                      (int)h1[0], (int)h1[1], (int)h1[2], (int)h1[3]};
#pragma unroll
        for (int l = 0; l < 8; ++l) {
            int tk = tok[l] & 511;                 // indices already in range
            offs[mt][l] = l * 524288 + tk * 1024;  // bytes into Tp
        }
    }

    floatx4 acc[2][16];
#pragma unroll
    for (int mt = 0; mt < 2; ++mt)
#pragma unroll
        for (int nt = 0; nt < 16; ++nt) acc[mt][nt] = (floatx4){0.f, 0.f, 0.f, 0.f};

    for (int kb = 0; kb < 4; ++kb) {
        __syncthreads();
        // stage W2t[:, kb*128 .. +128) -> LDS
#pragma unroll
        for (int i = 0; i < 16; ++i) {
            int flat = i * 2048 + t * 8;
            int n = flat >> 7, k = flat & 127;
            uintx4 v = *(const uintx4*)(W2t + n * 512 + kb * 128 + k);
            *(uintx4*)(w2_lds + n * 136 + k) = v;
        }
        __syncthreads();

#pragma unroll
        for (int kc = 0; kc < 4; ++kc) {
            const int k0 = kb * 128 + kc * 32 + q * 8;  // this lane's global k base
            float4 b1a = *(const float4*)(b1 + k0);
            float4 b1b = *(const float4*)(b1 + k0 + 4);

            short8 afrag[2];
#pragma unroll
            for (int mt = 0; mt < 2; ++mt) {
                // issue all 8 gathers, then combine
                uintx4 g[8];
#pragma unroll
                for (int l = 0; l < 8; ++l)
                    g[l] = *(const uintx4*)((const char*)Tp + (offs[mt][l] + k0 * 2));

                float ha[8] = {b1a.x, b1a.y, b1a.z, b1a.w, b1b.x, b1b.y, b1b.z, b1b.w};
#pragma unroll
                for (int l = 0; l < 8; ++l)
#pragma unroll
                    for (int j = 0; j < 4; ++j) {
                        ha[2 * j]     += bf_lo(g[l][j]);
                        ha[2 * j + 1] += bf_hi(g[l][j]);
                    }
#pragma unroll
                for (int j = 0; j < 8; ++j)
                    afrag[mt][j] = (short)f2bf(geluf(ha[j]));
            }

#pragma unroll
            for (int nt = 0; nt < 16; ++nt) {
                short8 bfrag = *(const short8*)(w2_lds + (nt * 16 + p) * 136 + kc * 32 + q * 8);
                acc[0][nt] = __builtin_amdgcn_mfma_f32_16x16x32_bf16(afrag[0], bfrag, acc[0][nt], 0, 0, 0);
                acc[1][nt] = __builtin_amdgcn_mfma_f32_16x16x32_bf16(afrag[1], bfrag, acc[1][nt], 0, 0, 0);
            }
        }
    }

    // epilogue: D row(M=sample) = q*4+r, col(N) = nt*16+p; add b2, store f32
#pragma unroll
    for (int nt = 0; nt < 16; ++nt) {
        int n = nt * 16 + p;
        float b2v = b2[n];
#pragma unroll
        for (int mt = 0; mt < 2; ++mt)
#pragma unroll
            for (int r = 0; r < 4; ++r) {
                int m = m_block + wave * 32 + mt * 16 + q * 4 + r;
                out[m * 256 + n] = acc[mt][nt][r] + b2v;
            }
    }
}

// ---------------------------------------------------------------------------
extern "C" void kernel_launch(void* const* d_in, const int* in_sizes, int n_in,
                              void* d_out, int out_size, void* d_ws, size_t ws_size,
                              hipStream_t stream) {
    const int*   hap    = (const int*)d_in[0];
    const float* tables = (const float*)d_in[1];
    const float* W1     = (const float*)d_in[2];
    const float* b1     = (const float*)d_in[3];
    const float* W2     = (const float*)d_in[4];
    const float* b2     = (const float*)d_in[5];
    float*       outp   = (float*)d_out;

    unsigned short* Tp  = (unsigned short*)d_ws;                        // 8*512*512 bf16 = 4 MB
    unsigned short* W2t = (unsigned short*)d_ws + NLOCI * VOCAB * HID;  // 256 KB

    k_fuse_tables<<<dim3(512), dim3(256), 0, stream>>>(tables, W1, Tp);
    k_transpose_w2<<<dim3(512), dim3(256), 0, stream>>>(W2, W2t);
    k_main<<<dim3(NSAMP / 128), dim3(256), 0, stream>>>(hap, Tp, b1, W2t, b2, outp);
}

// Round 3
// 317.701 us; speedup vs baseline: 1.4150x; 1.4150x over previous
//
#include <hip/hip_runtime.h>
#include <math.h>

typedef __attribute__((ext_vector_type(8))) short  short8;   // 8 bf16 (4 VGPRs) - MFMA A/B frag
typedef __attribute__((ext_vector_type(4))) float  floatx4;  // MFMA C/D frag
typedef __attribute__((ext_vector_type(4))) unsigned int uintx4; // 16B vector load

#define NLOCI 8
#define VOCAB 512
#define DDIM  256
#define HID   512
#define NSAMP (8192 * 16)

__device__ __forceinline__ float bf_lo(unsigned int w) {
    union { unsigned int u; float f; } c; c.u = w << 16; return c.f;
}
__device__ __forceinline__ float bf_hi(unsigned int w) {
    union { unsigned int u; float f; } c; c.u = w & 0xFFFF0000u; return c.f;
}
__device__ __forceinline__ unsigned short f2bf(float f) {
    union { float f; unsigned int u; } c; c.f = f;
    unsigned int u = c.u;
    return (unsigned short)((u + 0x7FFFu + ((u >> 16) & 1u)) >> 16);  // RNE
}
// tanh-form GELU: x*(1 - 1/(exp2(2*log2e*y)+1)), y = x*(c0 + c0*0.044715*x^2)
// max |diff vs erf-GELU| ~3e-4 << 0.109 threshold; graceful at +-inf.
__device__ __forceinline__ float gelu_fast(float x) {
    float t = x * x;
    float y = x * __builtin_fmaf(0.035677408f, t, 0.79788456f);
    float e = __builtin_amdgcn_exp2f(y * 2.8853901f);
    float r = __builtin_amdgcn_rcpf(e + 1.0f);
    return x - x * r;
}

// ---------------------------------------------------------------------------
// Kernel 1: Tp[l] = tables[l] (512x256) @ W1[l*256:(l+1)*256] (256x512), bf16.
// b1 folded into locus 0 (each locus contributes exactly one row to h).
// grid = 8 loci * 8 vblocks * 8 nblocks = 512 blocks, 256 threads.
// ---------------------------------------------------------------------------
__global__ __launch_bounds__(256) void k_fuse_tables(
    const float* __restrict__ tables,   // [8][512][256] f32
    const float* __restrict__ W1,       // [2048][512] f32
    const float* __restrict__ b1,       // [512] f32
    unsigned short* __restrict__ Tp)    // [8][512][512] bf16
{
    const int l  = blockIdx.x >> 6;
    const int v0 = ((blockIdx.x >> 3) & 7) * 64;
    const int n0 = (blockIdx.x & 7) * 64;

    __shared__ unsigned short a_lds[64 * 264];   // tables tile (bf16), pad +8
    __shared__ unsigned short bt_lds[64 * 264];  // W1^T tile: bt[n][k] (bf16)

    const int t = threadIdx.x;

    // stage A: 64 rows x 256 cols, f32 -> bf16, fully coalesced float4
    {
        const float* src = tables + (l * 512 + v0) * 256;
#pragma unroll
        for (int i = 0; i < 16; ++i) {
            int flat = i * 1024 + t * 4;
            int row = flat >> 8, col = flat & 255;
            float4 v = *(const float4*)(src + flat);
            ushort4 pk;
            pk.x = f2bf(v.x); pk.y = f2bf(v.y); pk.z = f2bf(v.z); pk.w = f2bf(v.w);
            *(ushort4*)(a_lds + row * 264 + col) = pk;
        }
    }
    // stage B^T with vector loads: thread (kq=t>>4, nq=t&15) reads float4 along n
    {
        const int kq = t >> 4, nq = t & 15;
#pragma unroll
        for (int i = 0; i < 16; ++i) {
            int k = i * 16 + kq;
            float4 w = *(const float4*)(W1 + (l * 256 + k) * 512 + n0 + nq * 4);
            bt_lds[(nq * 4 + 0) * 264 + k] = f2bf(w.x);
            bt_lds[(nq * 4 + 1) * 264 + k] = f2bf(w.y);
            bt_lds[(nq * 4 + 2) * 264 + k] = f2bf(w.z);
            bt_lds[(nq * 4 + 3) * 264 + k] = f2bf(w.w);
        }
    }
    __syncthreads();

    const int wave = t >> 6, lane = t & 63;
    const int p = lane & 15, q = lane >> 4;

    floatx4 acc[4];
#pragma unroll
    for (int nt = 0; nt < 4; ++nt) acc[nt] = (floatx4){0.f, 0.f, 0.f, 0.f};

#pragma unroll
    for (int kc = 0; kc < 8; ++kc) {
        short8 afrag = *(const short8*)(a_lds + (wave * 16 + p) * 264 + kc * 32 + q * 8);
#pragma unroll
        for (int nt = 0; nt < 4; ++nt) {
            short8 bfrag = *(const short8*)(bt_lds + (nt * 16 + p) * 264 + kc * 32 + q * 8);
            acc[nt] = __builtin_amdgcn_mfma_f32_16x16x32_bf16(afrag, bfrag, acc[nt], 0, 0, 0);
        }
    }

    // D: row(M=vocab) = q*4 + r, col(N) = nt*16 + p; fold b1 at l==0
#pragma unroll
    for (int nt = 0; nt < 4; ++nt) {
        int col = n0 + nt * 16 + p;
        float badd = (l == 0) ? b1[col] : 0.0f;
#pragma unroll
        for (int r = 0; r < 4; ++r) {
            int row = v0 + wave * 16 + q * 4 + r;
            Tp[(l * 512 + row) * 512 + col] = f2bf(acc[nt][r] + badd);
        }
    }
}

// ---------------------------------------------------------------------------
// Kernel 1b: W2t[n][k] = bf16(W2[k][n])
// ---------------------------------------------------------------------------
__global__ __launch_bounds__(256) void k_transpose_w2(
    const float* __restrict__ W2,        // [512][256] f32
    unsigned short* __restrict__ W2t)    // [256][512] bf16
{
    int tid = blockIdx.x * 256 + threadIdx.x;  // 131072
    int n = tid >> 9, k = tid & 511;
    W2t[tid] = f2bf(W2[k * 256 + n]);
}

// ---------------------------------------------------------------------------
// Kernel 2: fused gather + GELU + (h @ W2 + b2)
// block = 256 threads (4 waves), 16 samples/wave -> 64 samples/block
// grid = 131072/64 = 2048.  LDS 36.9KB, acc 64 regs -> target 3 blocks/CU.
// ---------------------------------------------------------------------------
__global__ __launch_bounds__(256, 3) void k_main(
    const int* __restrict__ hap,              // [131072][8] int32
    const unsigned short* __restrict__ Tp,    // [8][512][512] bf16 (b1 folded)
    const unsigned short* __restrict__ W2t,   // [256][512] bf16
    const float* __restrict__ b2,             // [256] f32
    float* __restrict__ out)                  // [131072][256] f32
{
    __shared__ unsigned short w2_lds[256 * 72];  // [n][k_local 0..63], pad->72

    const int t = threadIdx.x;
    const int wave = t >> 6, lane = t & 63;
    const int p = lane & 15, q = lane >> 4;
    const int m_base = blockIdx.x * 64 + wave * 16;

    // Per-lane byte offsets of the 8 Tp rows for this lane's sample (m = m_base+p)
    int offs[8];
    {
        const uintx4* hp = (const uintx4*)(hap + (m_base + p) * 8);
        uintx4 h0 = hp[0], h1 = hp[1];
        int tok[8] = {(int)h0[0], (int)h0[1], (int)h0[2], (int)h0[3],
                      (int)h1[0], (int)h1[1], (int)h1[2], (int)h1[3]};
#pragma unroll
        for (int l = 0; l < 8; ++l)
            offs[l] = l * 524288 + (tok[l] & 511) * 1024;  // bytes into Tp
    }

    floatx4 acc[16];
#pragma unroll
    for (int nt = 0; nt < 16; ++nt) acc[nt] = (floatx4){0.f, 0.f, 0.f, 0.f};

    for (int kb = 0; kb < 8; ++kb) {
        __syncthreads();
        // stage W2t[:, kb*64 .. +64) -> LDS (16B/thread x 8 iters)
#pragma unroll
        for (int i = 0; i < 8; ++i) {
            int flat = i * 2048 + t * 8;
            int n = flat >> 6, k = flat & 63;
            uintx4 v = *(const uintx4*)(W2t + n * 512 + kb * 64 + k);
            *(uintx4*)(w2_lds + n * 72 + k) = v;
        }
        __syncthreads();

#pragma unroll
        for (int kc = 0; kc < 2; ++kc) {
            const int k0 = kb * 64 + kc * 32 + q * 8;  // this lane's global k base

            uintx4 g[8];
#pragma unroll
            for (int l = 0; l < 8; ++l)
                g[l] = *(const uintx4*)((const char*)Tp + (offs[l] + k0 * 2));

            float ha[8];
#pragma unroll
            for (int j = 0; j < 4; ++j) {
                ha[2 * j]     = bf_lo(g[0][j]);
                ha[2 * j + 1] = bf_hi(g[0][j]);
            }
#pragma unroll
            for (int l = 1; l < 8; ++l)
#pragma unroll
                for (int j = 0; j < 4; ++j) {
                    ha[2 * j]     += bf_lo(g[l][j]);
                    ha[2 * j + 1] += bf_hi(g[l][j]);
                }

            short8 afrag;
#pragma unroll
            for (int j = 0; j < 8; ++j)
                afrag[j] = (short)f2bf(gelu_fast(ha[j]));

#pragma unroll
            for (int nt = 0; nt < 16; ++nt) {
                short8 bfrag = *(const short8*)(w2_lds + (nt * 16 + p) * 72 + kc * 32 + q * 8);
                acc[nt] = __builtin_amdgcn_mfma_f32_16x16x32_bf16(afrag, bfrag, acc[nt], 0, 0, 0);
            }
        }
    }

    // epilogue: D row(M=sample) = q*4+r, col(N) = nt*16+p; add b2, NT store f32
#pragma unroll
    for (int nt = 0; nt < 16; ++nt) {
        int n = nt * 16 + p;
        float b2v = b2[n];
#pragma unroll
        for (int r = 0; r < 4; ++r) {
            int m = m_base + q * 4 + r;
            __builtin_nontemporal_store(acc[nt][r] + b2v, out + m * 256 + n);
        }
    }
}

// ---------------------------------------------------------------------------
extern "C" void kernel_launch(void* const* d_in, const int* in_sizes, int n_in,
                              void* d_out, int out_size, void* d_ws, size_t ws_size,
                              hipStream_t stream) {
    const int*   hap    = (const int*)d_in[0];
    const float* tables = (const float*)d_in[1];
    const float* W1     = (const float*)d_in[2];
    const float* b1     = (const float*)d_in[3];
    const float* W2     = (const float*)d_in[4];
    const float* b2     = (const float*)d_in[5];
    float*       outp   = (float*)d_out;

    unsigned short* Tp  = (unsigned short*)d_ws;                        // 4 MB bf16
    unsigned short* W2t = (unsigned short*)d_ws + NLOCI * VOCAB * HID;  // 256 KB

    k_fuse_tables<<<dim3(512), dim3(256), 0, stream>>>(tables, W1, b1, Tp);
    k_transpose_w2<<<dim3(512), dim3(256), 0, stream>>>(W2, W2t);
    k_main<<<dim3(NSAMP / 64), dim3(256), 0, stream>>>(hap, Tp, W2t, b2, outp);
}

// Round 4
// 316.146 us; speedup vs baseline: 1.4220x; 1.0049x over previous
//
#include <hip/hip_runtime.h>
#include <math.h>

typedef __attribute__((ext_vector_type(8))) short  short8;   // 8 bf16 (4 VGPRs) - MFMA A/B frag
typedef __attribute__((ext_vector_type(4))) float  floatx4;  // MFMA C/D frag
typedef __attribute__((ext_vector_type(2))) float  float2v;  // packed pair (v_pk_add_f32)
typedef __attribute__((ext_vector_type(4))) unsigned int uintx4; // 16B vector load

#define NLOCI 8
#define VOCAB 512
#define DDIM  256
#define HID   512
#define NSAMP (8192 * 16)

__device__ __forceinline__ float bitsf(unsigned int u) {
    union { unsigned int u; float f; } c; c.u = u; return c.f;
}
__device__ __forceinline__ unsigned short f2bf(float f) {  // RNE (used in k1, cold path)
    union { float f; unsigned int u; } c; c.f = f;
    unsigned int u = c.u;
    return (unsigned short)((u + 0x7FFFu + ((u >> 16) & 1u)) >> 16);
}
__device__ __forceinline__ unsigned short f2bf_fast(float f) {  // round-half-up, 2 ops
    union { float f; unsigned int u; } c; c.f = f;
    return (unsigned short)((c.u + 0x8000u) >> 16);
}
// tanh-form GELU via exp2+rcp; |diff vs erf-GELU| ~3e-4 << threshold.
__device__ __forceinline__ float gelu_fast(float x) {
    float t = x * x;
    float y = x * __builtin_fmaf(0.035677408f, t, 0.79788456f);
    float e = __builtin_amdgcn_exp2f(y * 2.8853901f);
    float r = __builtin_amdgcn_rcpf(e + 1.0f);
    return x - x * r;
}
// async 16B/lane global->LDS DMA (lane i lands at lds_base + i*16)
__device__ __forceinline__ void async_copy16(const void* g, void* l) {
    __builtin_amdgcn_global_load_lds(
        (const __attribute__((address_space(1))) unsigned int*)g,
        (__attribute__((address_space(3))) unsigned int*)l, 16, 0, 0);
}

// ---------------------------------------------------------------------------
// Kernel 1: Tp[l] = tables[l] (512x256) @ W1[l*256:(l+1)*256] (256x512), bf16.
// b1 folded into locus 0. XOR-swizzled LDS tiles (32 chunks of 16B per row):
//   element (row, k) lives at row*256 + ((k>>3) ^ (row&31))*8 + (k&7)  [shorts]
// grid = 8 loci * 8 vblocks * 8 nblocks = 512 blocks, 256 threads.
// ---------------------------------------------------------------------------
__global__ __launch_bounds__(256) void k_fuse_tables(
    const float* __restrict__ tables,   // [8][512][256] f32
    const float* __restrict__ W1,       // [2048][512] f32
    const float* __restrict__ b1,       // [512] f32
    unsigned short* __restrict__ Tp)    // [8][512][512] bf16
{
    const int l  = blockIdx.x >> 6;
    const int v0 = ((blockIdx.x >> 3) & 7) * 64;
    const int n0 = (blockIdx.x & 7) * 64;

    __shared__ unsigned short a_lds[64 * 256];   // 32 KB, swizzled
    __shared__ unsigned short bt_lds[64 * 256];  // 32 KB, swizzled (bt[n][k])

    const int t = threadIdx.x;

    // ---- stage A (tables tile): float4 coalesced loads, conflict-free writes
    {
        const float* asrc = tables + (l * 512 + v0) * 256;
#pragma unroll
        for (int i = 0; i < 16; ++i) {
            int flat = i * 1024 + t * 4;
            int row = flat >> 8, k = flat & 255;
            float4 v = *(const float4*)(asrc + flat);
            ushort4 pk4;
            pk4.x = f2bf(v.x); pk4.y = f2bf(v.y); pk4.z = f2bf(v.z); pk4.w = f2bf(v.w);
            int chunkX = (k >> 3) ^ (row & 31);
            *(ushort4*)(a_lds + row * 256 + chunkX * 8 + (k & 7)) = pk4;
        }
    }
    // ---- stage B^T: bt[n][k] = bf16(W1[l*256+k][n0+n])
    // scalar loads fully coalesced across n (64 consecutive floats/wave);
    // one b128 conflict-free swizzled LDS write per 8 k.
    {
        const int n = t & 63;
        const int kq = (t >> 6) * 64;
        const float* bsrc = W1 + (l * 256) * 512 + n0 + n;
#pragma unroll
        for (int i = 0; i < 8; ++i) {
            int k0 = kq + i * 8;
            short8 pk8;
#pragma unroll
            for (int j = 0; j < 8; ++j)
                pk8[j] = (short)f2bf(bsrc[(k0 + j) * 512]);
            int chunkX = (k0 >> 3) ^ (n & 31);
            *(short8*)(bt_lds + n * 256 + chunkX * 8) = pk8;
        }
    }
    __syncthreads();

    const int wave = t >> 6, lane = t & 63;
    const int p = lane & 15, q = lane >> 4;
    const int arow = wave * 16 + p;

    floatx4 acc[4];
#pragma unroll
    for (int nt = 0; nt < 4; ++nt) acc[nt] = (floatx4){0.f, 0.f, 0.f, 0.f};

#pragma unroll
    for (int kc = 0; kc < 8; ++kc) {
        int cq = kc * 4 + q;
        short8 afrag = *(const short8*)(a_lds + arow * 256 + (cq ^ (arow & 31)) * 8);
#pragma unroll
        for (int nt = 0; nt < 4; ++nt) {
            int brow = nt * 16 + p;
            short8 bfrag = *(const short8*)(bt_lds + brow * 256 + (cq ^ (brow & 31)) * 8);
            acc[nt] = __builtin_amdgcn_mfma_f32_16x16x32_bf16(afrag, bfrag, acc[nt], 0, 0, 0);
        }
    }

    // D: row(M=vocab) = q*4 + r, col(N) = nt*16 + p; fold b1 at l==0
#pragma unroll
    for (int nt = 0; nt < 4; ++nt) {
        int col = n0 + nt * 16 + p;
        float badd = (l == 0) ? b1[col] : 0.0f;
#pragma unroll
        for (int r = 0; r < 4; ++r) {
            int row = v0 + wave * 16 + q * 4 + r;
            Tp[(l * 512 + row) * 512 + col] = f2bf(acc[nt][r] + badd);
        }
    }
}

// ---------------------------------------------------------------------------
// Kernel 1b: LDS-tiled transpose+cvt: out[c][r] = bf16(in[r][c]), in [R][C] f32.
// grid = (R/64, C/64), 256 threads. Coalesced reads AND writes.
// ---------------------------------------------------------------------------
__global__ __launch_bounds__(256) void k_transpose_cvt(
    const float* __restrict__ in, unsigned short* __restrict__ out, int R, int C)
{
    __shared__ float tile[64 * 65];
    const int t = threadIdx.x;
    const int r0 = blockIdx.x * 64, c0 = blockIdx.y * 64;

#pragma unroll
    for (int i = 0; i < 16; ++i) {
        int flat = i * 256 + t;
        int rr = flat >> 6, cc = flat & 63;
        tile[rr * 65 + cc] = in[(r0 + rr) * C + c0 + cc];
    }
    __syncthreads();
#pragma unroll
    for (int i = 0; i < 8; ++i) {
        int flat = i * 256 + t;
        int cc = flat >> 5, rp = (flat & 31) * 2;
        ushort2 v;
        v.x = f2bf(tile[rp * 65 + cc]);
        v.y = f2bf(tile[(rp + 1) * 65 + cc]);
        *(ushort2*)(out + (c0 + cc) * R + r0 + rp) = v;
    }
}

// ---------------------------------------------------------------------------
// Kernel 2: fused gather + GELU + (h @ W2 + b2)
// block = 256 threads (4 waves), 16 samples/wave -> 64 samples/block,
// grid = 2048.  LDS = 32 KB (XOR-swizzled W2 tile, 8 chunks/row),
// staged via global_load_lds DMA.  4 blocks/CU target.
// ---------------------------------------------------------------------------
__global__ __launch_bounds__(256, 4) void k_main(
    const int* __restrict__ hap,              // [131072][8] int32
    const unsigned short* __restrict__ Tp,    // [8][512][512] bf16 (b1 folded)
    const unsigned short* __restrict__ W2t,   // [256][512] bf16
    const float* __restrict__ b2,             // [256] f32
    float* __restrict__ out)                  // [131072][256] f32
{
    // w2 tile: [n=256][k_local=64] shorts; element (n,k) at
    //   n*64 + ((k>>3) ^ (n&7))*8 + (k&7)
    __shared__ unsigned short w2_lds[256 * 64];  // 32 KB exactly

    const int t = threadIdx.x;
    const int wave = t >> 6, lane = t & 63;
    const int p = lane & 15, q = lane >> 4;
    const int m_base = blockIdx.x * 64 + wave * 16;

    // ---- per-lane global base addresses of the 8 Tp rows (q-offset folded in)
    const char* gbase[8];
    {
        const uintx4* hp = (const uintx4*)(hap + (m_base + p) * 8);
        uintx4 h0 = hp[0], h1 = hp[1];
        int tok[8] = {(int)h0[0], (int)h0[1], (int)h0[2], (int)h0[3],
                      (int)h1[0], (int)h1[1], (int)h1[2], (int)h1[3]};
#pragma unroll
        for (int l = 0; l < 8; ++l)
            gbase[l] = (const char*)Tp + l * 524288 + (tok[l] & 511) * 1024 + q * 16;
    }

    // ---- DMA lane mapping for W2 staging (matches swizzle exactly):
    // call i: rows n = wave*64 + i*8 + (lane>>3); chunk j = (lane&7) ^ (lane>>3 & 7)
    const int drow = lane >> 3;
    const int j_sw = (lane & 7) ^ (drow & 7);
    const unsigned short* wsrc = W2t + (wave * 64 + drow) * 512 + j_sw * 8;

    // ---- B-frag LDS offset: row n=nt*16+p -> chunkX = (kc*4+q) ^ (p&7) (nt-free!)
    const int p7 = p & 7;

    floatx4 acc[16];
#pragma unroll
    for (int nt = 0; nt < 16; ++nt) acc[nt] = (floatx4){0.f, 0.f, 0.f, 0.f};

    for (int kb = 0; kb < 8; ++kb) {
        __syncthreads();  // prior tile fully consumed
#pragma unroll
        for (int i = 0; i < 8; ++i)
            async_copy16(wsrc + kb * 64 + i * 8 * 512,
                         w2_lds + (wave * 64 + i * 8) * 64);
        __syncthreads();  // drains DMA (vmcnt) + syncs

#pragma unroll
        for (int kc = 0; kc < 2; ++kc) {
            const int koff = (kb * 64 + kc * 32) * 2;  // byte offset, fits load imm

            uintx4 g[8];
#pragma unroll
            for (int l = 0; l < 8; ++l)
                g[l] = *(const uintx4*)(gbase[l] + koff);

            // packed accumulate: s[j] = sum over loci of (lo,hi) pairs
            float2v s[4];
#pragma unroll
            for (int j = 0; j < 4; ++j)
                s[j] = (float2v){bitsf(g[0][j] << 16), bitsf(g[0][j] & 0xFFFF0000u)};
#pragma unroll
            for (int l = 1; l < 8; ++l)
#pragma unroll
                for (int j = 0; j < 4; ++j) {
                    float2v u = (float2v){bitsf(g[l][j] << 16), bitsf(g[l][j] & 0xFFFF0000u)};
                    s[j] += u;
                }

            short8 afrag;
#pragma unroll
            for (int j = 0; j < 4; ++j) {
                afrag[2 * j]     = (short)f2bf_fast(gelu_fast(s[j][0]));
                afrag[2 * j + 1] = (short)f2bf_fast(gelu_fast(s[j][1]));
            }

            const unsigned short* bbase =
                w2_lds + p * 64 + (((kc * 4 + q) ^ p7) * 8);
#pragma unroll
            for (int nt = 0; nt < 16; ++nt) {
                short8 bfrag = *(const short8*)(bbase + nt * 1024);  // folds into ds offset
                acc[nt] = __builtin_amdgcn_mfma_f32_16x16x32_bf16(afrag, bfrag, acc[nt], 0, 0, 0);
            }
        }
    }

    // epilogue: D row(M=sample) = q*4+r, col(N) = nt*16+p; add b2, NT store f32
#pragma unroll
    for (int nt = 0; nt < 16; ++nt) {
        int n = nt * 16 + p;
        float b2v = b2[n];
#pragma unroll
        for (int r = 0; r < 4; ++r) {
            int m = m_base + q * 4 + r;
            __builtin_nontemporal_store(acc[nt][r] + b2v, out + m * 256 + n);
        }
    }
}

// ---------------------------------------------------------------------------
extern "C" void kernel_launch(void* const* d_in, const int* in_sizes, int n_in,
                              void* d_out, int out_size, void* d_ws, size_t ws_size,
                              hipStream_t stream) {
    const int*   hap    = (const int*)d_in[0];
    const float* tables = (const float*)d_in[1];
    const float* W1     = (const float*)d_in[2];
    const float* b1     = (const float*)d_in[3];
    const float* W2     = (const float*)d_in[4];
    const float* b2     = (const float*)d_in[5];
    float*       outp   = (float*)d_out;

    unsigned short* Tp  = (unsigned short*)d_ws;                        // 4 MB bf16
    unsigned short* W2t = (unsigned short*)d_ws + NLOCI * VOCAB * HID;  // 256 KB

    k_fuse_tables<<<dim3(512), dim3(256), 0, stream>>>(tables, W1, b1, Tp);
    k_transpose_cvt<<<dim3(8, 4), dim3(256), 0, stream>>>(W2, W2t, HID, DDIM);
    k_main<<<dim3(NSAMP / 64), dim3(256), 0, stream>>>(hap, Tp, W2t, b2, outp);
}